// Round 5
// baseline (491.831 us; speedup 1.0000x reference)
//
#include <hip/hip_runtime.h>
#include <hip/hip_bf16.h>
#include <stdint.h>

// ---------------------------------------------------------------------------
// RWKV self-attention: fused mix -> GEMM (bf16 MFMA) x3 -> WKV -> out GEMM
// B=4, T=2048, H=2048.
// GEMM: 256x256 tile, BK=64, 8 waves (2Mx4N), 16x16x32 bf16 MFMA,
// 8-phase pipelined schedule (T3) with counted vmcnt(6) (T4), XOR-swizzled
// LDS chunks (T2, conflict-free), s_setprio around MFMA clusters (T5),
// global_load_lds width=16 staging, XCD-patch block swizzle (T1).
// R5 = R4 resubmitted verbatim (R4 bench was an infra failure: "MI355X
// container failed twice" — no kernel signal; one-variable-per-round).
// R4 = exact R2 GEMM schedule (69us, 996 TF). R3's end-of-phase register
// prefetch REGRESSED (+440cy/phase): ds_read writing VGPRs still sourced by
// in-flight MFMAs is a WAR hazard -> matrix-pipe drain every phase. Do NOT
// reload fragment registers immediately after their MFMA cluster; no
// register headroom to double-buffer (128 VGPR + 128 AGPR = 256 = budget).
// Schedule ledger (per iteration, kt=2*it, buf0=kt, buf1=kt+1):
//   ph1 (b0,qi0,qj0) reads A0+B0 (12 ds) | stage A[kt+1]-qi1 -> buf1
//   ph2 (b0,qi0,qj1) reads B1 (4 ds)     | stage A[kt+2]-qi0 -> buf0
//   ph3 (b0,qi1,qj0) reads A1 (8 ds)     | stage B[kt+2]-qj0 -> buf0
//   ph4 (b0,qi1,qj1) no reads            | stage B[kt+2]-qj1 -> buf0 | vmcnt(6)
//   ph5 (b1,qi0,qj0) reads A0+B0        | stage A[kt+2]-qi1 -> buf0
//   ph6 (b1,qi0,qj1) reads B1           | stage A[kt+3]-qi0 -> buf1
//   ph7 (b1,qi1,qj0) reads A1           | stage B[kt+3]-qj0 -> buf1
//   ph8 (b1,qi1,qj1) no reads           | stage B[kt+3]-qj1 -> buf1 | vmcnt(6)
// End-of-phase lgkmcnt(0) = WAR fence before the closing barrier.
// Last iteration peeled: only ph1's stage, vmcnt(0) at ph4.
// WKV: 2-pass chunked scan. pass2 folded into pass3 (R3: removed the
// 32-block latency-bound pass2 dispatch, ~90us saved). R4: one-exp combine —
// max-subtraction makes one exp argument exactly 0, so compute the single
// exp(-|d|) and select (bit-identical, halves v_exp_f32 count).
// Workspace (unchanged, known-safe): WT 8.4MB + 4 x 33.5MB = 142.6 MB.
// ---------------------------------------------------------------------------

typedef short short8 __attribute__((ext_vector_type(8)));   // 8 bf16 (4 VGPRs)
typedef float f32x4 __attribute__((ext_vector_type(4)));

#define WKV_C 32  // chunks per sequence (L = T/WKV_C = 64)

__device__ __forceinline__ void gld_lds16(const void* gptr, void* lptr) {
  void* g = const_cast<void*>(gptr);
  __builtin_amdgcn_global_load_lds(
      (__attribute__((address_space(1))) void*)g,
      (__attribute__((address_space(3))) void*)lptr, 16, 0, 0);
}

__device__ __forceinline__ unsigned short f2bf(float f) {
  __bf16 b = (__bf16)f;
  return __builtin_bit_cast(unsigned short, b);
}
__device__ __forceinline__ unsigned short f2h(float f) {
  _Float16 h = (_Float16)f;
  return __builtin_bit_cast(unsigned short, h);
}
__device__ __forceinline__ float h2f(unsigned short u) {
  return (float)__builtin_bit_cast(_Float16, u);
}

// ---------------- weight transpose + fp32->bf16 cast -----------------------
__global__ void transpose_cast(const float* __restrict__ W,
                               unsigned short* __restrict__ WT, int n) {
  __shared__ float tile[32][33];
  const int tx = threadIdx.x, ty = threadIdx.y;
  const int x = blockIdx.x * 32 + tx;
#pragma unroll
  for (int j = 0; j < 32; j += 8) {
    int row = blockIdx.y * 32 + ty + j;
    tile[ty + j][tx] = W[(size_t)row * n + x];
  }
  __syncthreads();
#pragma unroll
  for (int j = 0; j < 32; j += 8) {
    int orow = blockIdx.x * 32 + ty + j;  // n index
    int ocol = blockIdx.y * 32 + tx;      // k index
    WT[(size_t)orow * n + ocol] = f2bf(tile[tx][ty + j]);
  }
}

// ---------------- fused time-shift mix: hidden read ONCE, 3 outputs --------
__global__ void mix3_kernel(const float4* __restrict__ hid,
                            const float4* __restrict__ mk4,
                            const float4* __restrict__ mv4,
                            const float4* __restrict__ mr4,
                            ushort4* __restrict__ xk, ushort4* __restrict__ xv,
                            ushort4* __restrict__ xr, int T, int H4) {
  size_t idx = (size_t)blockIdx.x * blockDim.x + threadIdx.x;
  int c4 = (int)(idx % H4);
  int t = (int)(idx / H4) % T;
  float4 h = hid[idx];
  float4 p = make_float4(0.f, 0.f, 0.f, 0.f);
  if (t != 0) p = hid[idx - H4];
  float4 mk = mk4[c4], mv = mv4[c4], mr = mr4[c4];
  ushort4 ok, ov, orr;
  ok.x = f2bf(h.x * mk.x + p.x * (1.f - mk.x));
  ok.y = f2bf(h.y * mk.y + p.y * (1.f - mk.y));
  ok.z = f2bf(h.z * mk.z + p.z * (1.f - mk.z));
  ok.w = f2bf(h.w * mk.w + p.w * (1.f - mk.w));
  ov.x = f2bf(h.x * mv.x + p.x * (1.f - mv.x));
  ov.y = f2bf(h.y * mv.y + p.y * (1.f - mv.y));
  ov.z = f2bf(h.z * mv.z + p.z * (1.f - mv.z));
  ov.w = f2bf(h.w * mv.w + p.w * (1.f - mv.w));
  orr.x = f2bf(h.x * mr.x + p.x * (1.f - mr.x));
  orr.y = f2bf(h.y * mr.y + p.y * (1.f - mr.y));
  orr.z = f2bf(h.z * mr.z + p.z * (1.f - mr.z));
  orr.w = f2bf(h.w * mr.w + p.w * (1.f - mr.w));
  xk[idx] = ok;
  xv[idx] = ov;
  xr[idx] = orr;
}

// ---------------- bf16 MFMA GEMM: C[MxN] = A[MxK] * Bt[NxK]^T --------------
#define MODE_F32 0
#define MODE_F16 1
#define MODE_F16_SIG 2

#define GK 2048  // compile-time K
#define GN 2048  // compile-time N (C leading dim)

// --- 256^2 8-phase kernel helper macros ---
// Stage one 16KB consumption unit (2 x 8KB global_load_lds sweeps).
#define STAGE_A(kt_, u, b)                                                     \
  {                                                                            \
    _Pragma("unroll") for (int s_ = 0; s_ < 2; ++s_)                           \
        gld_lds16(Ab + (s_ * 128 + (u) * 64) * GK + (kt_) * 64,                \
                  ldsT + (b) * 16384 + (s_ * 128 + (u) * 64) * 64);            \
  }
#define STAGE_B(kt_, u, b)                                                     \
  {                                                                            \
    _Pragma("unroll") for (int s_ = 0; s_ < 2; ++s_)                           \
        gld_lds16(Bb + (s_ * 128 + (u) * 32) * GK + (kt_) * 64,                \
                  ldsT + 32768 + (b) * 16384 + ((u) * 128 + s_ * 64) * 64);    \
  }

#define LOAD_A(b, qi)                                                          \
  {                                                                            \
    _Pragma("unroll") for (int ip_ = 0; ip_ < 4; ++ip_) {                      \
      aF[ip_][0] =                                                             \
          *(const short8*)(pA0 + (b) * 16384 + (qi) * 4096 + ip_ * 1024);      \
      aF[ip_][1] =                                                             \
          *(const short8*)(pA1 + (b) * 16384 + (qi) * 4096 + ip_ * 1024);      \
    }                                                                          \
  }
#define LOAD_B(b, qj, dst)                                                     \
  {                                                                            \
    _Pragma("unroll") for (int jj_ = 0; jj_ < 2; ++jj_) {                      \
      dst[jj_][0] =                                                            \
          *(const short8*)(pB0 + (b) * 16384 + (qj) * 8192 + jj_ * 1024);      \
      dst[jj_][1] =                                                            \
          *(const short8*)(pB1 + (b) * 16384 + (qj) * 8192 + jj_ * 1024);      \
    }                                                                          \
  }

#define MFMA16(qi, qj, bfr)                                                    \
  {                                                                            \
    _Pragma("unroll") for (int ip_ = 0; ip_ < 4; ++ip_)                        \
        _Pragma("unroll") for (int jj_ = 0; jj_ < 2; ++jj_) {                  \
      acc[(qi) * 4 + ip_][(qj) * 2 + jj_] =                                    \
          __builtin_amdgcn_mfma_f32_16x16x32_bf16(                             \
              aF[ip_][0], bfr[jj_][0], acc[(qi) * 4 + ip_][(qj) * 2 + jj_],    \
              0, 0, 0);                                                        \
      acc[(qi) * 4 + ip_][(qj) * 2 + jj_] =                                    \
          __builtin_amdgcn_mfma_f32_16x16x32_bf16(                             \
              aF[ip_][1], bfr[jj_][1], acc[(qi) * 4 + ip_][(qj) * 2 + jj_],    \
              0, 0, 0);                                                        \
    }                                                                          \
  }

// Phase: {stage; ds-reads; barrier; [vmcnt]; setprio(1); 16 MFMA (compiler
//         inserts fine-grained lgkmcnt); setprio(0); lgkmcnt(0); barrier}
// End-of-phase lgkmcnt(0) = WAR fence: all reads of this phase's regions
// drain before any later phase's global_load_lds can overwrite them.
#define PHASE(b, qi, qj, STG, WAITN)                                           \
  {                                                                            \
    STG;                                                                       \
    if ((qi) == 0 && (qj) == 0) { LOAD_A(b, 0); LOAD_B(b, 0, bF0); }           \
    if ((qi) == 0 && (qj) == 1) { LOAD_B(b, 1, bF1); }                         \
    if ((qi) == 1 && (qj) == 0) { LOAD_A(b, 1); }                              \
    __builtin_amdgcn_s_barrier();                                              \
    if ((WAITN) == 6) asm volatile("s_waitcnt vmcnt(6)" ::: "memory");         \
    if ((WAITN) == 0) asm volatile("s_waitcnt vmcnt(0)" ::: "memory");         \
    __builtin_amdgcn_s_setprio(1);                                             \
    if ((qj) == 0) { MFMA16(qi, 0, bF0); } else { MFMA16(qi, 1, bF1); }        \
    __builtin_amdgcn_s_setprio(0);                                             \
    asm volatile("s_waitcnt lgkmcnt(0)" ::: "memory");                         \
    __builtin_amdgcn_s_barrier();                                              \
  }

#define ITER(kt, LAST)                                                         \
  {                                                                            \
    PHASE(0, 0, 0, STAGE_A((kt) + 1, 1, 1), -1);                               \
    PHASE(0, 0, 1, if (!(LAST)) STAGE_A((kt) + 2, 0, 0), -1);                  \
    PHASE(0, 1, 0, if (!(LAST)) STAGE_B((kt) + 2, 0, 0), -1);                  \
    PHASE(0, 1, 1, if (!(LAST)) STAGE_B((kt) + 2, 1, 0), (LAST) ? 0 : 6);      \
    PHASE(1, 0, 0, if (!(LAST)) STAGE_A((kt) + 2, 1, 0), -1);                  \
    PHASE(1, 0, 1, if (!(LAST)) STAGE_A((kt) + 3, 0, 1), -1);                  \
    PHASE(1, 1, 0, if (!(LAST)) STAGE_B((kt) + 3, 0, 1), -1);                  \
    PHASE(1, 1, 1, if (!(LAST)) STAGE_B((kt) + 3, 1, 1), (LAST) ? -1 : 6);     \
  }

template <int MODE>
__global__ __launch_bounds__(512, 2) void gemm_bt(
    const unsigned short* __restrict__ A, const unsigned short* __restrict__ Bt,
    void* __restrict__ Cv) {
  // A: [2 bufs][256 rows][64 cols] @ elem 0; B: same @ elem 32768.
  // B rows stored qj-permuted: lds row L = qj*128 + wn*32 + jj*16 + lm
  //   <-> global row r = ((L>>5)&3)*64 + (L>>7)*32 + (L&31).
  // Chunk XOR swizzle: LDS[row][pc] = global[row][pc ^ (row&7)] (8-elem chunks).
  __shared__ unsigned short ldsm[65536];  // 128 KiB

  const int t = threadIdx.x;
  const int lane = t & 63;
  const int wave = t >> 6;
  const int wm = wave >> 2;   // 0..1 (M half of block tile)
  const int wn = wave & 3;    // 0..3 (N quarter)
  const int quad = lane >> 4;
  const int lm = lane & 15;
  const int sw = lm & 7;

  // XCD-patch swizzle: grid (8,32) = 256 blocks = 1/CU; each lin%8 class
  // (assumed XCD round-robin) gets a contiguous 4M x 8N tile patch.
  const int lin = blockIdx.y * 8 + blockIdx.x;  // 0..255
  const int cls = lin & 7;
  const int q = lin >> 3;                       // 0..31
  const int mTile = cls * 4 + (q & 3);          // 0..31
  const int nTile = q >> 2;                     // 0..7
  const size_t mBase = (size_t)mTile * 256;
  const size_t nBase = (size_t)nTile * 256;

  // per-thread staging offsets (elements). Sweep covers 64 lds rows x 64 cols:
  // thread t -> lds row base+(t>>3), phys chunk t&7, global chunk swizzled.
  const int lr = t >> 3;
  const int swz = (t & 7) ^ (lr & 7);
  const unsigned short* Ab = A + mBase * GK + lr * GK + swz * 8;
  const unsigned short* Bb =
      Bt + nBase * GK + (lr >> 5) * 64 * GK + (lr & 31) * GK + swz * 8;
  unsigned short* ldsT = ldsm + t * 8;

  // fragment read vaddrs (one per matrix per kk; sub-tiles via imm offsets)
  const unsigned short* pA0 = ldsm + (wm * 128 + lm) * 64 + ((0 + quad) ^ sw) * 8;
  const unsigned short* pA1 = ldsm + (wm * 128 + lm) * 64 + ((4 + quad) ^ sw) * 8;
  const unsigned short* pB0 =
      ldsm + 32768 + (wn * 32 + lm) * 64 + ((0 + quad) ^ sw) * 8;
  const unsigned short* pB1 =
      ldsm + 32768 + (wn * 32 + lm) * 64 + ((4 + quad) ^ sw) * 8;

  short8 aF[4][2];        // current qi half: 4 i' x 2 kk
  short8 bF0[2][2];       // qj=0: 2 jj x 2 kk (held through phase 4 reuse)
  short8 bF1[2][2];       // qj=1
  f32x4 acc[8][4];
#pragma unroll
  for (int i = 0; i < 8; ++i)
#pragma unroll
    for (int j = 0; j < 4; ++j) {
      f32x4 zz = {0.f, 0.f, 0.f, 0.f};
      acc[i][j] = zz;
    }

  // prologue: kt0 all 4 units, then kt1's first 3 units; vmcnt(6) -> kt0 landed
  STAGE_A(0, 0, 0);
  STAGE_B(0, 0, 0);
  STAGE_B(0, 1, 0);
  STAGE_A(0, 1, 0);
  STAGE_A(1, 0, 1);
  STAGE_B(1, 0, 1);
  STAGE_B(1, 1, 1);
  asm volatile("s_waitcnt vmcnt(6)" ::: "memory");
  __builtin_amdgcn_s_barrier();

  const int KT = GK >> 6;  // 32 K-tiles of 64
  int kt = 0;
#pragma unroll 1
  for (; kt + 2 < KT; kt += 2) { ITER(kt, 0); }
  ITER(kt, 1);  // peeled: only ph1 stage, vmcnt(0) at ph4

  // epilogue: C/D layout col=lane&15, row=quad*4+reg  [m89/m91 verified]
#pragma unroll
  for (int i = 0; i < 8; ++i) {
    const size_t row = mBase + wm * 128 + (i >> 2) * 64 + (i & 3) * 16 + quad * 4;
#pragma unroll
    for (int j = 0; j < 4; ++j) {
      const size_t col = nBase + wn * 64 + (j >> 1) * 32 + (j & 1) * 16 + lm;
#pragma unroll
      for (int rg = 0; rg < 4; ++rg) {
        float x = acc[i][j][rg];
        size_t off = (row + rg) * GN + col;
        if (MODE == MODE_F32) {
          ((float*)Cv)[off] = x;
        } else {
          if (MODE == MODE_F16_SIG) x = 1.0f / (1.0f + __expf(-x));
          ((unsigned short*)Cv)[off] = f2h(x);
        }
      }
    }
  }
}

// ---------------- WKV pass 1: per-chunk summary from zero state ------------
// One-exp combine: mfs = max(mtd, kt) makes one exp arg exactly 0 ->
// exp(-|mtd-kt|) once + select. Bit-identical to two-exp form.
__global__ void wkv_pass1(const unsigned short* __restrict__ kk,
                          const unsigned short* __restrict__ vv,
                          const float* __restrict__ tdec,
                          float* __restrict__ pn, float* __restrict__ pd,
                          float* __restrict__ pm, int T, int H, int L) {
  int idx = blockIdx.x * blockDim.x + threadIdx.x;  // [0, B*C*H)
  int h = idx % H;
  int bc = idx / H;
  int c = bc % WKV_C;
  int b = bc / WKV_C;
  const float td = -__expf(tdec[h]);
  size_t base = ((size_t)b * T + (size_t)c * L) * H + h;
  const unsigned short* kp = kk + base;
  const unsigned short* vp = vv + base;
  float num = 0.f, den = 0.f, mx = -1e38f;
#pragma unroll 8
  for (int t = 0; t < L; ++t) {
    float kt = h2f(kp[(size_t)t * H]);
    float vt = h2f(vp[(size_t)t * H]);
    float mtd = mx + td;
    float d = mtd - kt;
    float e = __expf(-fabsf(d));
    float e1s = d >= 0.f ? 1.f : e;
    float e2s = d >= 0.f ? e : 1.f;
    num = e1s * num + e2s * vt;
    den = e1s * den + e2s;
    mx = fmaxf(mtd, kt);
  }
  pn[idx] = num;
  pd[idx] = den;
  pm[idx] = mx;
}

// ---------------- WKV pass 3 (pass2 folded in): prefix + replay, emit y ----
__global__ void wkv_pass3(const unsigned short* __restrict__ kk,
                          const unsigned short* __restrict__ vv,
                          const unsigned short* rr,
                          const float* __restrict__ pn,
                          const float* __restrict__ pd,
                          const float* __restrict__ pm,
                          const float* __restrict__ tdec,
                          const float* __restrict__ tfir, unsigned short* y,
                          int T, int H, int L) {
  int idx = blockIdx.x * blockDim.x + threadIdx.x;  // [0, B*C*H)
  int h = idx % H;
  int bc = idx / H;
  int c = bc % WKV_C;
  int b = bc / WKV_C;
  const float td = -__expf(tdec[h]);
  const float tf = tfir[h];
  // inline chunk-prefix (was pass2): combine chunks 0..c-1, same order/math.
  const float Ltd = td * (float)L;
  float num = 0.f, den = 0.f, mx = -1e38f;
  for (int cp = 0; cp < c; ++cp) {
    size_t o = ((size_t)b * WKV_C + cp) * H + h;
    float mtd = mx + Ltd;
    float cm = pm[o];
    float d = mtd - cm;
    float e = __expf(-fabsf(d));
    float e1 = d >= 0.f ? 1.f : e;
    float e2 = d >= 0.f ? e : 1.f;
    num = e1 * num + e2 * pn[o];
    den = e1 * den + e2 * pd[o];
    mx = fmaxf(mtd, cm);
  }
  size_t base = ((size_t)b * T + (size_t)c * L) * H + h;
  const unsigned short* kp = kk + base;
  const unsigned short* vp = vv + base;
  const unsigned short* rp = rr + base;
  unsigned short* yp = y + base;
#pragma unroll 4
  for (int t = 0; t < L; ++t) {
    size_t o = (size_t)t * H;
    float kt = h2f(kp[o]);
    float vt = h2f(vp[o]);
    float rt = h2f(rp[o]);
    float ktf = kt + tf;
    // output combine (one exp): mfo = max(mx, ktf)
    float d = mx - ktf;
    float e = __expf(-fabsf(d));
    float e1 = d >= 0.f ? 1.f : e;
    float e2 = d >= 0.f ? e : 1.f;
    float out = __fdividef(e1 * num + e2 * vt, e1 * den + e2);
    yp[o] = f2bf(rt * out);
    // state update (one exp): mfs = max(mtd, kt)
    float mtd = mx + td;
    float d2 = mtd - kt;
    float e_ = __expf(-fabsf(d2));
    float e1s = d2 >= 0.f ? 1.f : e_;
    float e2s = d2 >= 0.f ? e_ : 1.f;
    num = e1s * num + e2s * vt;
    den = e1s * den + e2s;
    mx = fmaxf(mtd, kt);
  }
}

// ---------------------------------------------------------------------------
extern "C" void kernel_launch(void* const* d_in, const int* in_sizes, int n_in,
                              void* d_out, int out_size, void* d_ws,
                              size_t ws_size, hipStream_t stream) {
  const int Bb = 4, T = 2048, H = 2048;
  const int M = Bb * T;      // 8192
  const int L = T / WKV_C;   // 64

  const float* hidden = (const float*)d_in[0];
  const float* time_decay = (const float*)d_in[1];
  const float* time_first = (const float*)d_in[2];
  const float* tmk = (const float*)d_in[3];
  const float* tmv = (const float*)d_in[4];
  const float* tmr = (const float*)d_in[5];
  const float* Wk = (const float*)d_in[6];
  const float* Wv = (const float*)d_in[7];
  const float* Wr = (const float*)d_in[8];
  const float* Wo = (const float*)d_in[9];
  float* out = (float*)d_out;

  const size_t szWT = (size_t)H * H * 2;   // 8.4 MB
  const size_t szMH = (size_t)M * H * 2;   // 33.5 MB
  const size_t need = szWT + 4 * szMH + 1024;
  if (ws_size < need) return;  // diagnostic guard

  char* ws = (char*)d_ws;
  size_t off = 0;
  auto alloc = [&](size_t bytes) {
    char* p = ws + off;
    off += (bytes + 255) & ~(size_t)255;
    return p;
  };
  unsigned short* WT = (unsigned short*)alloc(szWT);
  unsigned short* A1 = (unsigned short*)alloc(szMH);  // xk, later vbuf
  unsigned short* A2 = (unsigned short*)alloc(szMH);  // xv, later rbuf/y
  unsigned short* A3 = (unsigned short*)alloc(szMH);  // xr, later chunk arrays
  unsigned short* A4 = (unsigned short*)alloc(szMH);  // kbuf

  unsigned short* xk = A1;
  unsigned short* xv = A2;
  unsigned short* xr = A3;
  unsigned short* kbuf = A4;
  unsigned short* vbuf = A1;  // xk dead after GEMM-k
  unsigned short* rbuf = A2;  // xv dead after GEMM-v; y in-place later

  // chunk-scan arrays in A3 (xr dead after GEMM-r): 3 MB << 33.5 MB.
  const size_t nCH = (size_t)Bb * WKV_C * H;  // 262144
  float* pn = (float*)A3;
  float* pd = pn + nCH;
  float* pm = pd + nCH;

  const dim3 txG(H / 32, H / 32), txB(32, 8);
  const int H4 = H / 4;
  const dim3 gmG(H / 256, M / 256), gmB(512);

  // fused mix (hidden read once)
  mix3_kernel<<<dim3((M * H4) / 256), dim3(256), 0, stream>>>(
      (const float4*)hidden, (const float4*)tmk, (const float4*)tmv,
      (const float4*)tmr, (ushort4*)xk, (ushort4*)xv, (ushort4*)xr, T, H4);

  // k path
  transpose_cast<<<txG, txB, 0, stream>>>(Wk, WT, H);
  gemm_bt<MODE_F16><<<gmG, gmB, 0, stream>>>(xk, WT, kbuf);
  // v path (writes over dead xk)
  transpose_cast<<<txG, txB, 0, stream>>>(Wv, WT, H);
  gemm_bt<MODE_F16><<<gmG, gmB, 0, stream>>>(xv, WT, vbuf);
  // r path (sigmoid fused; writes over dead xv)
  transpose_cast<<<txG, txB, 0, stream>>>(Wr, WT, H);
  gemm_bt<MODE_F16_SIG><<<gmG, gmB, 0, stream>>>(xr, WT, rbuf);

  // WKV chunked parallel scan (xr region now dead -> chunk arrays there)
  const int nThreads1 = Bb * WKV_C * H;  // 262144
  wkv_pass1<<<dim3(nThreads1 / 256), dim3(256), 0, stream>>>(
      kbuf, vbuf, time_decay, pn, pd, pm, T, H, L);
  wkv_pass3<<<dim3(nThreads1 / 256), dim3(256), 0, stream>>>(
      kbuf, vbuf, rbuf, pn, pd, pm, time_decay, time_first, rbuf, T, H, L);

  // output GEMM: out = y @ Wo (fp32 out)
  transpose_cast<<<txG, txB, 0, stream>>>(Wo, WT, H);
  gemm_bt<MODE_F32><<<gmG, gmB, 0, stream>>>(rbuf, WT, out);
}

// Round 6
// 486.272 us; speedup vs baseline: 1.0114x; 1.0114x over previous
//
#include <hip/hip_runtime.h>
#include <hip/hip_bf16.h>
#include <stdint.h>

// ---------------------------------------------------------------------------
// RWKV self-attention: fused mix -> GEMM (bf16 MFMA) x3 -> WKV -> out GEMM
// B=4, T=2048, H=2048.
// GEMM: 256x256 tile, BK=64, 8 waves (2Mx4N), 16x16x32 bf16 MFMA,
// 8-phase pipelined schedule (T3) with counted vmcnt(6) (T4), XOR-swizzled
// LDS chunks (T2, conflict-free), s_setprio around MFMA clusters (T5),
// global_load_lds width=16 staging, XCD-patch block swizzle (T1).
// R6 change: SINGLE barrier per phase (was 2). Ledger-verified:
//  - RAW: every region's ds_reads occur after a {vmcnt + barrier} that
//    retires its staging (ph4/ph8 carry the vmcnt and have NO reads, so all
//    reads are downstream of the guarantee). Checked per-region, both bufs,
//    non-LAST and LAST (vmcnt(0)@ph4 covers buf1 for ph5-7 of LAST).
//  - WAR: every region has lgkm(0) + >=1 barrier between last read and
//    overwriting stage (A00 read ph1 -> staged ph2 is the tightest: 1 bar).
//  - Phase order: READS; STAGE; [vmcnt]; setprio1; MFMA; setprio0; lgkm(0);
//    barrier. Reads at top feed this phase's MFMA (compiler emits fine
//    lgkmcnt); waves decouple across the removed barrier -> sibling-wave
//    MFMA/mem overlap; setprio arbitrates (T5 role-split now real).
// R4 lesson kept: do NOT reload fragment regs right after their MFMA cluster
// (register-WAR drains matrix pipe); no headroom to double-buffer
// (128 VGPR + 128 AGPR = 256 = budget at 2 waves/SIMD).
// Cross-round lesson (R5): rocprof dispatch times != bench times (replay,
// cold caches). Only within-round counter comparisons + bench totals count.
// Schedule ledger (per iteration, kt=2*it, buf0=kt, buf1=kt+1):
//   ph1 reads A0+B0(buf0) | stage A[kt+1]-qi1 -> buf1
//   ph2 reads B1(buf0)    | stage A[kt+2]-qi0 -> buf0
//   ph3 reads A1(buf0)    | stage B[kt+2]-qj0 -> buf0
//   ph4 no reads          | stage B[kt+2]-qj1 -> buf0 | vmcnt(6)
//   ph5 reads A0+B0(buf1) | stage A[kt+2]-qi1 -> buf0
//   ph6 reads B1(buf1)    | stage A[kt+3]-qi0 -> buf1
//   ph7 reads A1(buf1)    | stage B[kt+3]-qj0 -> buf1
//   ph8 no reads          | stage B[kt+3]-qj1 -> buf1 | vmcnt(6)
// Last iteration peeled: only ph1's stage, vmcnt(0) at ph4.
// WKV: 2-pass chunked scan, pass2 folded into pass3 (R3-verified two-exp
// form restored; R5's one-exp variant removed as a variable).
// Workspace (unchanged, known-safe): WT 8.4MB + 4 x 33.5MB = 142.6 MB.
// ---------------------------------------------------------------------------

typedef short short8 __attribute__((ext_vector_type(8)));   // 8 bf16 (4 VGPRs)
typedef float f32x4 __attribute__((ext_vector_type(4)));

#define WKV_C 32  // chunks per sequence (L = T/WKV_C = 64)

__device__ __forceinline__ void gld_lds16(const void* gptr, void* lptr) {
  void* g = const_cast<void*>(gptr);
  __builtin_amdgcn_global_load_lds(
      (__attribute__((address_space(1))) void*)g,
      (__attribute__((address_space(3))) void*)lptr, 16, 0, 0);
}

__device__ __forceinline__ unsigned short f2bf(float f) {
  __bf16 b = (__bf16)f;
  return __builtin_bit_cast(unsigned short, b);
}
__device__ __forceinline__ unsigned short f2h(float f) {
  _Float16 h = (_Float16)f;
  return __builtin_bit_cast(unsigned short, h);
}
__device__ __forceinline__ float h2f(unsigned short u) {
  return (float)__builtin_bit_cast(_Float16, u);
}

// ---------------- weight transpose + fp32->bf16 cast -----------------------
__global__ void transpose_cast(const float* __restrict__ W,
                               unsigned short* __restrict__ WT, int n) {
  __shared__ float tile[32][33];
  const int tx = threadIdx.x, ty = threadIdx.y;
  const int x = blockIdx.x * 32 + tx;
#pragma unroll
  for (int j = 0; j < 32; j += 8) {
    int row = blockIdx.y * 32 + ty + j;
    tile[ty + j][tx] = W[(size_t)row * n + x];
  }
  __syncthreads();
#pragma unroll
  for (int j = 0; j < 32; j += 8) {
    int orow = blockIdx.x * 32 + ty + j;  // n index
    int ocol = blockIdx.y * 32 + tx;      // k index
    WT[(size_t)orow * n + ocol] = f2bf(tile[tx][ty + j]);
  }
}

// ---------------- fused time-shift mix: hidden read ONCE, 3 outputs --------
__global__ void mix3_kernel(const float4* __restrict__ hid,
                            const float4* __restrict__ mk4,
                            const float4* __restrict__ mv4,
                            const float4* __restrict__ mr4,
                            ushort4* __restrict__ xk, ushort4* __restrict__ xv,
                            ushort4* __restrict__ xr, int T, int H4) {
  size_t idx = (size_t)blockIdx.x * blockDim.x + threadIdx.x;
  int c4 = (int)(idx % H4);
  int t = (int)(idx / H4) % T;
  float4 h = hid[idx];
  float4 p = make_float4(0.f, 0.f, 0.f, 0.f);
  if (t != 0) p = hid[idx - H4];
  float4 mk = mk4[c4], mv = mv4[c4], mr = mr4[c4];
  ushort4 ok, ov, orr;
  ok.x = f2bf(h.x * mk.x + p.x * (1.f - mk.x));
  ok.y = f2bf(h.y * mk.y + p.y * (1.f - mk.y));
  ok.z = f2bf(h.z * mk.z + p.z * (1.f - mk.z));
  ok.w = f2bf(h.w * mk.w + p.w * (1.f - mk.w));
  ov.x = f2bf(h.x * mv.x + p.x * (1.f - mv.x));
  ov.y = f2bf(h.y * mv.y + p.y * (1.f - mv.y));
  ov.z = f2bf(h.z * mv.z + p.z * (1.f - mv.z));
  ov.w = f2bf(h.w * mv.w + p.w * (1.f - mv.w));
  orr.x = f2bf(h.x * mr.x + p.x * (1.f - mr.x));
  orr.y = f2bf(h.y * mr.y + p.y * (1.f - mr.y));
  orr.z = f2bf(h.z * mr.z + p.z * (1.f - mr.z));
  orr.w = f2bf(h.w * mr.w + p.w * (1.f - mr.w));
  xk[idx] = ok;
  xv[idx] = ov;
  xr[idx] = orr;
}

// ---------------- bf16 MFMA GEMM: C[MxN] = A[MxK] * Bt[NxK]^T --------------
#define MODE_F32 0
#define MODE_F16 1
#define MODE_F16_SIG 2

#define GK 2048  // compile-time K
#define GN 2048  // compile-time N (C leading dim)

// --- 256^2 8-phase kernel helper macros ---
// Stage one 16KB consumption unit (2 x 8KB global_load_lds sweeps).
#define STAGE_A(kt_, u, b)                                                     \
  {                                                                            \
    _Pragma("unroll") for (int s_ = 0; s_ < 2; ++s_)                           \
        gld_lds16(Ab + (s_ * 128 + (u) * 64) * GK + (kt_) * 64,                \
                  ldsT + (b) * 16384 + (s_ * 128 + (u) * 64) * 64);            \
  }
#define STAGE_B(kt_, u, b)                                                     \
  {                                                                            \
    _Pragma("unroll") for (int s_ = 0; s_ < 2; ++s_)                           \
        gld_lds16(Bb + (s_ * 128 + (u) * 32) * GK + (kt_) * 64,                \
                  ldsT + 32768 + (b) * 16384 + ((u) * 128 + s_ * 64) * 64);    \
  }

#define LOAD_A(b, qi)                                                          \
  {                                                                            \
    _Pragma("unroll") for (int ip_ = 0; ip_ < 4; ++ip_) {                      \
      aF[ip_][0] =                                                             \
          *(const short8*)(pA0 + (b) * 16384 + (qi) * 4096 + ip_ * 1024);      \
      aF[ip_][1] =                                                             \
          *(const short8*)(pA1 + (b) * 16384 + (qi) * 4096 + ip_ * 1024);      \
    }                                                                          \
  }
#define LOAD_B(b, qj, dst)                                                     \
  {                                                                            \
    _Pragma("unroll") for (int jj_ = 0; jj_ < 2; ++jj_) {                      \
      dst[jj_][0] =                                                            \
          *(const short8*)(pB0 + (b) * 16384 + (qj) * 8192 + jj_ * 1024);      \
      dst[jj_][1] =                                                            \
          *(const short8*)(pB1 + (b) * 16384 + (qj) * 8192 + jj_ * 1024);      \
    }                                                                          \
  }

#define MFMA16(qi, qj, bfr)                                                    \
  {                                                                            \
    _Pragma("unroll") for (int ip_ = 0; ip_ < 4; ++ip_)                        \
        _Pragma("unroll") for (int jj_ = 0; jj_ < 2; ++jj_) {                  \
      acc[(qi) * 4 + ip_][(qj) * 2 + jj_] =                                    \
          __builtin_amdgcn_mfma_f32_16x16x32_bf16(                             \
              aF[ip_][0], bfr[jj_][0], acc[(qi) * 4 + ip_][(qj) * 2 + jj_],    \
              0, 0, 0);                                                        \
      acc[(qi) * 4 + ip_][(qj) * 2 + jj_] =                                    \
          __builtin_amdgcn_mfma_f32_16x16x32_bf16(                             \
              aF[ip_][1], bfr[jj_][1], acc[(qi) * 4 + ip_][(qj) * 2 + jj_],    \
              0, 0, 0);                                                        \
    }                                                                          \
  }

// Phase: {ds-reads; stage; [vmcnt]; setprio(1); 16 MFMA (compiler inserts
//         fine-grained lgkmcnt); setprio(0); lgkm(0) WAR fence; ONE barrier}
#define PHASE(b, qi, qj, STG, WAITN)                                           \
  {                                                                            \
    if ((qi) == 0 && (qj) == 0) { LOAD_A(b, 0); LOAD_B(b, 0, bF0); }           \
    if ((qi) == 0 && (qj) == 1) { LOAD_B(b, 1, bF1); }                         \
    if ((qi) == 1 && (qj) == 0) { LOAD_A(b, 1); }                              \
    STG;                                                                       \
    if ((WAITN) == 6) asm volatile("s_waitcnt vmcnt(6)" ::: "memory");         \
    if ((WAITN) == 0) asm volatile("s_waitcnt vmcnt(0)" ::: "memory");         \
    __builtin_amdgcn_s_setprio(1);                                             \
    if ((qj) == 0) { MFMA16(qi, 0, bF0); } else { MFMA16(qi, 1, bF1); }        \
    __builtin_amdgcn_s_setprio(0);                                             \
    asm volatile("s_waitcnt lgkmcnt(0)" ::: "memory");                         \
    __builtin_amdgcn_s_barrier();                                              \
  }

#define ITER(kt, LAST)                                                         \
  {                                                                            \
    PHASE(0, 0, 0, STAGE_A((kt) + 1, 1, 1), -1);                               \
    PHASE(0, 0, 1, if (!(LAST)) STAGE_A((kt) + 2, 0, 0), -1);                  \
    PHASE(0, 1, 0, if (!(LAST)) STAGE_B((kt) + 2, 0, 0), -1);                  \
    PHASE(0, 1, 1, if (!(LAST)) STAGE_B((kt) + 2, 1, 0), (LAST) ? 0 : 6);      \
    PHASE(1, 0, 0, if (!(LAST)) STAGE_A((kt) + 2, 1, 0), -1);                  \
    PHASE(1, 0, 1, if (!(LAST)) STAGE_A((kt) + 3, 0, 1), -1);                  \
    PHASE(1, 1, 0, if (!(LAST)) STAGE_B((kt) + 3, 0, 1), -1);                  \
    PHASE(1, 1, 1, if (!(LAST)) STAGE_B((kt) + 3, 1, 1), (LAST) ? -1 : 6);     \
  }

template <int MODE>
__global__ __launch_bounds__(512, 2) void gemm_bt(
    const unsigned short* __restrict__ A, const unsigned short* __restrict__ Bt,
    void* __restrict__ Cv) {
  // A: [2 bufs][256 rows][64 cols] @ elem 0; B: same @ elem 32768.
  // B rows stored qj-permuted: lds row L = qj*128 + wn*32 + jj*16 + lm
  //   <-> global row r = ((L>>5)&3)*64 + (L>>7)*32 + (L&31).
  // Chunk XOR swizzle: LDS[row][pc] = global[row][pc ^ (row&7)] (8-elem chunks).
  __shared__ unsigned short ldsm[65536];  // 128 KiB

  const int t = threadIdx.x;
  const int lane = t & 63;
  const int wave = t >> 6;
  const int wm = wave >> 2;   // 0..1 (M half of block tile)
  const int wn = wave & 3;    // 0..3 (N quarter)
  const int quad = lane >> 4;
  const int lm = lane & 15;
  const int sw = lm & 7;

  // XCD-patch swizzle: grid (8,32) = 256 blocks = 1/CU; each lin%8 class
  // (assumed XCD round-robin) gets a contiguous 4M x 8N tile patch.
  const int lin = blockIdx.y * 8 + blockIdx.x;  // 0..255
  const int cls = lin & 7;
  const int q = lin >> 3;                       // 0..31
  const int mTile = cls * 4 + (q & 3);          // 0..31
  const int nTile = q >> 2;                     // 0..7
  const size_t mBase = (size_t)mTile * 256;
  const size_t nBase = (size_t)nTile * 256;

  // per-thread staging offsets (elements). Sweep covers 64 lds rows x 64 cols:
  // thread t -> lds row base+(t>>3), phys chunk t&7, global chunk swizzled.
  const int lr = t >> 3;
  const int swz = (t & 7) ^ (lr & 7);
  const unsigned short* Ab = A + mBase * GK + lr * GK + swz * 8;
  const unsigned short* Bb =
      Bt + nBase * GK + (lr >> 5) * 64 * GK + (lr & 31) * GK + swz * 8;
  unsigned short* ldsT = ldsm + t * 8;

  // fragment read vaddrs (one per matrix per kk; sub-tiles via imm offsets)
  const unsigned short* pA0 = ldsm + (wm * 128 + lm) * 64 + ((0 + quad) ^ sw) * 8;
  const unsigned short* pA1 = ldsm + (wm * 128 + lm) * 64 + ((4 + quad) ^ sw) * 8;
  const unsigned short* pB0 =
      ldsm + 32768 + (wn * 32 + lm) * 64 + ((0 + quad) ^ sw) * 8;
  const unsigned short* pB1 =
      ldsm + 32768 + (wn * 32 + lm) * 64 + ((4 + quad) ^ sw) * 8;

  short8 aF[4][2];        // current qi half: 4 i' x 2 kk
  short8 bF0[2][2];       // qj=0: 2 jj x 2 kk (held through phase 4 reuse)
  short8 bF1[2][2];       // qj=1
  f32x4 acc[8][4];
#pragma unroll
  for (int i = 0; i < 8; ++i)
#pragma unroll
    for (int j = 0; j < 4; ++j) {
      f32x4 zz = {0.f, 0.f, 0.f, 0.f};
      acc[i][j] = zz;
    }

  // prologue: kt0 all 4 units, then kt1's first 3 units; vmcnt(6) -> kt0 landed
  STAGE_A(0, 0, 0);
  STAGE_B(0, 0, 0);
  STAGE_B(0, 1, 0);
  STAGE_A(0, 1, 0);
  STAGE_A(1, 0, 1);
  STAGE_B(1, 0, 1);
  STAGE_B(1, 1, 1);
  asm volatile("s_waitcnt vmcnt(6)" ::: "memory");
  __builtin_amdgcn_s_barrier();

  const int KT = GK >> 6;  // 32 K-tiles of 64
  int kt = 0;
#pragma unroll 1
  for (; kt + 2 < KT; kt += 2) { ITER(kt, 0); }
  ITER(kt, 1);  // peeled: only ph1 stage, vmcnt(0) at ph4

  // epilogue: C/D layout col=lane&15, row=quad*4+reg  [m89/m91 verified]
#pragma unroll
  for (int i = 0; i < 8; ++i) {
    const size_t row = mBase + wm * 128 + (i >> 2) * 64 + (i & 3) * 16 + quad * 4;
#pragma unroll
    for (int j = 0; j < 4; ++j) {
      const size_t col = nBase + wn * 64 + (j >> 1) * 32 + (j & 1) * 16 + lm;
#pragma unroll
      for (int rg = 0; rg < 4; ++rg) {
        float x = acc[i][j][rg];
        size_t off = (row + rg) * GN + col;
        if (MODE == MODE_F32) {
          ((float*)Cv)[off] = x;
        } else {
          if (MODE == MODE_F16_SIG) x = 1.0f / (1.0f + __expf(-x));
          ((unsigned short*)Cv)[off] = f2h(x);
        }
      }
    }
  }
}

// ---------------- WKV pass 1: per-chunk summary from zero state ------------
__global__ void wkv_pass1(const unsigned short* __restrict__ kk,
                          const unsigned short* __restrict__ vv,
                          const float* __restrict__ tdec,
                          float* __restrict__ pn, float* __restrict__ pd,
                          float* __restrict__ pm, int T, int H, int L) {
  int idx = blockIdx.x * blockDim.x + threadIdx.x;  // [0, B*C*H)
  int h = idx % H;
  int bc = idx / H;
  int c = bc % WKV_C;
  int b = bc / WKV_C;
  const float td = -__expf(tdec[h]);
  size_t base = ((size_t)b * T + (size_t)c * L) * H + h;
  const unsigned short* kp = kk + base;
  const unsigned short* vp = vv + base;
  float num = 0.f, den = 0.f, mx = -1e38f;
#pragma unroll 8
  for (int t = 0; t < L; ++t) {
    float kt = h2f(kp[(size_t)t * H]);
    float vt = h2f(vp[(size_t)t * H]);
    float mtd = mx + td;
    float mfs = fmaxf(mtd, kt);
    float e1s = __expf(mtd - mfs);
    float e2s = __expf(kt - mfs);
    num = e1s * num + e2s * vt;
    den = e1s * den + e2s;
    mx = mfs;
  }
  pn[idx] = num;
  pd[idx] = den;
  pm[idx] = mx;
}

// ---------------- WKV pass 3 (pass2 folded in): prefix + replay, emit y ----
__global__ void wkv_pass3(const unsigned short* __restrict__ kk,
                          const unsigned short* __restrict__ vv,
                          const unsigned short* rr,
                          const float* __restrict__ pn,
                          const float* __restrict__ pd,
                          const float* __restrict__ pm,
                          const float* __restrict__ tdec,
                          const float* __restrict__ tfir, unsigned short* y,
                          int T, int H, int L) {
  int idx = blockIdx.x * blockDim.x + threadIdx.x;  // [0, B*C*H)
  int h = idx % H;
  int bc = idx / H;
  int c = bc % WKV_C;
  int b = bc / WKV_C;
  const float td = -__expf(tdec[h]);
  const float tf = tfir[h];
  // inline chunk-prefix (was pass2): combine chunks 0..c-1, same order/math.
  const float Ltd = td * (float)L;
  float num = 0.f, den = 0.f, mx = -1e38f;
  for (int cp = 0; cp < c; ++cp) {
    size_t o = ((size_t)b * WKV_C + cp) * H + h;
    float mtd = mx + Ltd;
    float cm = pm[o];
    float mnew = fmaxf(mtd, cm);
    float e1 = __expf(mtd - mnew);
    float e2 = __expf(cm - mnew);
    num = e1 * num + e2 * pn[o];
    den = e1 * den + e2 * pd[o];
    mx = mnew;
  }
  size_t base = ((size_t)b * T + (size_t)c * L) * H + h;
  const unsigned short* kp = kk + base;
  const unsigned short* vp = vv + base;
  const unsigned short* rp = rr + base;
  unsigned short* yp = y + base;
#pragma unroll 4
  for (int t = 0; t < L; ++t) {
    size_t o = (size_t)t * H;
    float kt = h2f(kp[o]);
    float vt = h2f(vp[o]);
    float rt = h2f(rp[o]);
    float ktf = kt + tf;
    float mfo = fmaxf(mx, ktf);
    float e1 = __expf(mx - mfo);
    float e2 = __expf(ktf - mfo);
    float out = __fdividef(e1 * num + e2 * vt, e1 * den + e2);
    yp[o] = f2bf(rt * out);
    float mtd = mx + td;
    float mfs = fmaxf(mtd, kt);
    float e1s = __expf(mtd - mfs);
    float e2s = __expf(kt - mfs);
    num = e1s * num + e2s * vt;
    den = e1s * den + e2s;
    mx = mfs;
  }
}

// ---------------------------------------------------------------------------
extern "C" void kernel_launch(void* const* d_in, const int* in_sizes, int n_in,
                              void* d_out, int out_size, void* d_ws,
                              size_t ws_size, hipStream_t stream) {
  const int Bb = 4, T = 2048, H = 2048;
  const int M = Bb * T;      // 8192
  const int L = T / WKV_C;   // 64

  const float* hidden = (const float*)d_in[0];
  const float* time_decay = (const float*)d_in[1];
  const float* time_first = (const float*)d_in[2];
  const float* tmk = (const float*)d_in[3];
  const float* tmv = (const float*)d_in[4];
  const float* tmr = (const float*)d_in[5];
  const float* Wk = (const float*)d_in[6];
  const float* Wv = (const float*)d_in[7];
  const float* Wr = (const float*)d_in[8];
  const float* Wo = (const float*)d_in[9];
  float* out = (float*)d_out;

  const size_t szWT = (size_t)H * H * 2;   // 8.4 MB
  const size_t szMH = (size_t)M * H * 2;   // 33.5 MB
  const size_t need = szWT + 4 * szMH + 1024;
  if (ws_size < need) return;  // diagnostic guard

  char* ws = (char*)d_ws;
  size_t off = 0;
  auto alloc = [&](size_t bytes) {
    char* p = ws + off;
    off += (bytes + 255) & ~(size_t)255;
    return p;
  };
  unsigned short* WT = (unsigned short*)alloc(szWT);
  unsigned short* A1 = (unsigned short*)alloc(szMH);  // xk, later vbuf
  unsigned short* A2 = (unsigned short*)alloc(szMH);  // xv, later rbuf/y
  unsigned short* A3 = (unsigned short*)alloc(szMH);  // xr, later chunk arrays
  unsigned short* A4 = (unsigned short*)alloc(szMH);  // kbuf

  unsigned short* xk = A1;
  unsigned short* xv = A2;
  unsigned short* xr = A3;
  unsigned short* kbuf = A4;
  unsigned short* vbuf = A1;  // xk dead after GEMM-k
  unsigned short* rbuf = A2;  // xv dead after GEMM-v; y in-place later

  // chunk-scan arrays in A3 (xr dead after GEMM-r): 3 MB << 33.5 MB.
  const size_t nCH = (size_t)Bb * WKV_C * H;  // 262144
  float* pn = (float*)A3;
  float* pd = pn + nCH;
  float* pm = pd + nCH;

  const dim3 txG(H / 32, H / 32), txB(32, 8);
  const int H4 = H / 4;
  const dim3 gmG(H / 256, M / 256), gmB(512);

  // fused mix (hidden read once)
  mix3_kernel<<<dim3((M * H4) / 256), dim3(256), 0, stream>>>(
      (const float4*)hidden, (const float4*)tmk, (const float4*)tmv,
      (const float4*)tmr, (ushort4*)xk, (ushort4*)xv, (ushort4*)xr, T, H4);

  // k path
  transpose_cast<<<txG, txB, 0, stream>>>(Wk, WT, H);
  gemm_bt<MODE_F16><<<gmG, gmB, 0, stream>>>(xk, WT, kbuf);
  // v path (writes over dead xk)
  transpose_cast<<<txG, txB, 0, stream>>>(Wv, WT, H);
  gemm_bt<MODE_F16><<<gmG, gmB, 0, stream>>>(xv, WT, vbuf);
  // r path (sigmoid fused; writes over dead xv)
  transpose_cast<<<txG, txB, 0, stream>>>(Wr, WT, H);
  gemm_bt<MODE_F16_SIG><<<gmG, gmB, 0, stream>>>(xr, WT, rbuf);

  // WKV chunked parallel scan (xr region now dead -> chunk arrays there)
  const int nThreads1 = Bb * WKV_C * H;  // 262144
  wkv_pass1<<<dim3(nThreads1 / 256), dim3(256), 0, stream>>>(
      kbuf, vbuf, time_decay, pn, pd, pm, T, H, L);
  wkv_pass3<<<dim3(nThreads1 / 256), dim3(256), 0, stream>>>(
      kbuf, vbuf, rbuf, pn, pd, pm, time_decay, time_first, rbuf, T, H, L);

  // output GEMM: out = y @ Wo (fp32 out)
  transpose_cast<<<txG, txB, 0, stream>>>(Wo, WT, H);
  gemm_bt<MODE_F32><<<gmG, gmB, 0, stream>>>(rbuf, WT, out);
}

// Round 7
// 482.503 us; speedup vs baseline: 1.0193x; 1.0078x over previous
//
#include <hip/hip_runtime.h>
#include <hip/hip_bf16.h>
#include <stdint.h>

// ---------------------------------------------------------------------------
// RWKV self-attention: fused mix -> GEMM (bf16 MFMA) x3 -> WKV -> out GEMM
// B=4, T=2048, H=2048.
// GEMM: 256x256 tile, BK=64, 8 waves (2Mx4N), 16x16x32 bf16 MFMA,
// 8-phase pipelined schedule (T3) with counted vmcnt(6) (T4), XOR-swizzled
// LDS chunks (T2, conflict-free), s_setprio around MFMA clusters (T5),
// global_load_lds width=16 staging, XCD-patch block swizzle (T1).
// R7 change: m201-EXACT phase gate (the one untested schedule variant):
//   {reads; stage; [lgkm(8) if 12-read phase]; BARRIER; [vmcnt];
//    hard lgkm(0); setprio1; 16 MFMA; setprio0; BARRIER}
// vs R6's single-barrier compiler-scheduled gate (42% MfmaUtil, 1100cy/ph
// vs m201's 824). Reads issue in their own slot and overlap the PREVIOUS
// phase's draining MFMA pipe (s_barrier waits on issue, not completion);
// hard lgkm(0) aligns both waves before the MFMA burst. NO sched_barrier
// (R1's killer, per m137/m141). Reads are C++ loads -> compiler still
// tracks deps (rule-18 inline-asm hazard not applicable).
// Ledger (2-barrier form) re-verified:
//  - RAW: every region's reads sit after the {vmcnt(6|0) + barrier} that
//    retires its staging (prologue vmcnt(6) covers ph1's buf0 reads).
//  - WAR (no end fence needed): region read at phase p is hard-completed by
//    lgkm(0) inside p; overwriting stage issues at q>=p+1 top, after
//    barrier2(p). Tightest: A00 read ph1 -> staged ph2. Safe.
// R4 lesson kept: no fragment-register reload right after the MFMA cluster
// (register-WAR drains matrix pipe); no headroom to double-buffer frags
// (128 VGPR + 128 AGPR = 256 = budget at 2 waves/SIMD).
// Cross-round lesson (R5): rocprof dispatch times != bench times; only
// within-round counter comparisons + bench totals count.
// Schedule ledger (per iteration, kt=2*it, buf0=kt, buf1=kt+1):
//   ph1 reads A0+B0(buf0) | stage A[kt+1]-qi1 -> buf1
//   ph2 reads B1(buf0)    | stage A[kt+2]-qi0 -> buf0
//   ph3 reads A1(buf0)    | stage B[kt+2]-qj0 -> buf0
//   ph4 no reads          | stage B[kt+2]-qj1 -> buf0 | vmcnt(6)
//   ph5 reads A0+B0(buf1) | stage A[kt+2]-qi1 -> buf0
//   ph6 reads B1(buf1)    | stage A[kt+3]-qi0 -> buf1
//   ph7 reads A1(buf1)    | stage B[kt+3]-qj0 -> buf1
//   ph8 no reads          | stage B[kt+3]-qj1 -> buf1 | vmcnt(6)
// Last iteration peeled: only ph1's stage, vmcnt(0) at ph4.
// WKV: 2-pass chunked scan, pass2 folded into pass3 (R3-verified two-exp).
// Workspace (unchanged, known-safe): WT 8.4MB + 4 x 33.5MB = 142.6 MB.
// ---------------------------------------------------------------------------

typedef short short8 __attribute__((ext_vector_type(8)));   // 8 bf16 (4 VGPRs)
typedef float f32x4 __attribute__((ext_vector_type(4)));

#define WKV_C 32  // chunks per sequence (L = T/WKV_C = 64)

__device__ __forceinline__ void gld_lds16(const void* gptr, void* lptr) {
  void* g = const_cast<void*>(gptr);
  __builtin_amdgcn_global_load_lds(
      (__attribute__((address_space(1))) void*)g,
      (__attribute__((address_space(3))) void*)lptr, 16, 0, 0);
}

__device__ __forceinline__ unsigned short f2bf(float f) {
  __bf16 b = (__bf16)f;
  return __builtin_bit_cast(unsigned short, b);
}
__device__ __forceinline__ unsigned short f2h(float f) {
  _Float16 h = (_Float16)f;
  return __builtin_bit_cast(unsigned short, h);
}
__device__ __forceinline__ float h2f(unsigned short u) {
  return (float)__builtin_bit_cast(_Float16, u);
}

// ---------------- weight transpose + fp32->bf16 cast -----------------------
__global__ void transpose_cast(const float* __restrict__ W,
                               unsigned short* __restrict__ WT, int n) {
  __shared__ float tile[32][33];
  const int tx = threadIdx.x, ty = threadIdx.y;
  const int x = blockIdx.x * 32 + tx;
#pragma unroll
  for (int j = 0; j < 32; j += 8) {
    int row = blockIdx.y * 32 + ty + j;
    tile[ty + j][tx] = W[(size_t)row * n + x];
  }
  __syncthreads();
#pragma unroll
  for (int j = 0; j < 32; j += 8) {
    int orow = blockIdx.x * 32 + ty + j;  // n index
    int ocol = blockIdx.y * 32 + tx;      // k index
    WT[(size_t)orow * n + ocol] = f2bf(tile[tx][ty + j]);
  }
}

// ---------------- fused time-shift mix: hidden read ONCE, 3 outputs --------
__global__ void mix3_kernel(const float4* __restrict__ hid,
                            const float4* __restrict__ mk4,
                            const float4* __restrict__ mv4,
                            const float4* __restrict__ mr4,
                            ushort4* __restrict__ xk, ushort4* __restrict__ xv,
                            ushort4* __restrict__ xr, int T, int H4) {
  size_t idx = (size_t)blockIdx.x * blockDim.x + threadIdx.x;
  int c4 = (int)(idx % H4);
  int t = (int)(idx / H4) % T;
  float4 h = hid[idx];
  float4 p = make_float4(0.f, 0.f, 0.f, 0.f);
  if (t != 0) p = hid[idx - H4];
  float4 mk = mk4[c4], mv = mv4[c4], mr = mr4[c4];
  ushort4 ok, ov, orr;
  ok.x = f2bf(h.x * mk.x + p.x * (1.f - mk.x));
  ok.y = f2bf(h.y * mk.y + p.y * (1.f - mk.y));
  ok.z = f2bf(h.z * mk.z + p.z * (1.f - mk.z));
  ok.w = f2bf(h.w * mk.w + p.w * (1.f - mk.w));
  ov.x = f2bf(h.x * mv.x + p.x * (1.f - mv.x));
  ov.y = f2bf(h.y * mv.y + p.y * (1.f - mv.y));
  ov.z = f2bf(h.z * mv.z + p.z * (1.f - mv.z));
  ov.w = f2bf(h.w * mv.w + p.w * (1.f - mv.w));
  orr.x = f2bf(h.x * mr.x + p.x * (1.f - mr.x));
  orr.y = f2bf(h.y * mr.y + p.y * (1.f - mr.y));
  orr.z = f2bf(h.z * mr.z + p.z * (1.f - mr.z));
  orr.w = f2bf(h.w * mr.w + p.w * (1.f - mr.w));
  xk[idx] = ok;
  xv[idx] = ov;
  xr[idx] = orr;
}

// ---------------- bf16 MFMA GEMM: C[MxN] = A[MxK] * Bt[NxK]^T --------------
#define MODE_F32 0
#define MODE_F16 1
#define MODE_F16_SIG 2

#define GK 2048  // compile-time K
#define GN 2048  // compile-time N (C leading dim)

// --- 256^2 8-phase kernel helper macros ---
// Stage one 16KB consumption unit (2 x 8KB global_load_lds sweeps).
#define STAGE_A(kt_, u, b)                                                     \
  {                                                                            \
    _Pragma("unroll") for (int s_ = 0; s_ < 2; ++s_)                           \
        gld_lds16(Ab + (s_ * 128 + (u) * 64) * GK + (kt_) * 64,                \
                  ldsT + (b) * 16384 + (s_ * 128 + (u) * 64) * 64);            \
  }
#define STAGE_B(kt_, u, b)                                                     \
  {                                                                            \
    _Pragma("unroll") for (int s_ = 0; s_ < 2; ++s_)                           \
        gld_lds16(Bb + (s_ * 128 + (u) * 32) * GK + (kt_) * 64,                \
                  ldsT + 32768 + (b) * 16384 + ((u) * 128 + s_ * 64) * 64);    \
  }

#define LOAD_A(b, qi)                                                          \
  {                                                                            \
    _Pragma("unroll") for (int ip_ = 0; ip_ < 4; ++ip_) {                      \
      aF[ip_][0] =                                                             \
          *(const short8*)(pA0 + (b) * 16384 + (qi) * 4096 + ip_ * 1024);      \
      aF[ip_][1] =                                                             \
          *(const short8*)(pA1 + (b) * 16384 + (qi) * 4096 + ip_ * 1024);      \
    }                                                                          \
  }
#define LOAD_B(b, qj, dst)                                                     \
  {                                                                            \
    _Pragma("unroll") for (int jj_ = 0; jj_ < 2; ++jj_) {                      \
      dst[jj_][0] =                                                            \
          *(const short8*)(pB0 + (b) * 16384 + (qj) * 8192 + jj_ * 1024);      \
      dst[jj_][1] =                                                            \
          *(const short8*)(pB1 + (b) * 16384 + (qj) * 8192 + jj_ * 1024);      \
    }                                                                          \
  }

#define MFMA16(qi, qj, bfr)                                                    \
  {                                                                            \
    _Pragma("unroll") for (int ip_ = 0; ip_ < 4; ++ip_)                        \
        _Pragma("unroll") for (int jj_ = 0; jj_ < 2; ++jj_) {                  \
      acc[(qi) * 4 + ip_][(qj) * 2 + jj_] =                                    \
          __builtin_amdgcn_mfma_f32_16x16x32_bf16(                             \
              aF[ip_][0], bfr[jj_][0], acc[(qi) * 4 + ip_][(qj) * 2 + jj_],    \
              0, 0, 0);                                                        \
      acc[(qi) * 4 + ip_][(qj) * 2 + jj_] =                                    \
          __builtin_amdgcn_mfma_f32_16x16x32_bf16(                             \
              aF[ip_][1], bfr[jj_][1], acc[(qi) * 4 + ip_][(qj) * 2 + jj_],    \
              0, 0, 0);                                                        \
    }                                                                          \
  }

// Phase (m201 gate): {reads; stage; [lgkm(8) if 12-read]; barrier; [vmcnt];
//                     hard lgkm(0); setprio1; 16 MFMA; setprio0; barrier}
#define PHASE(b, qi, qj, STG, WAITN)                                           \
  {                                                                            \
    if ((qi) == 0 && (qj) == 0) { LOAD_A(b, 0); LOAD_B(b, 0, bF0); }           \
    if ((qi) == 0 && (qj) == 1) { LOAD_B(b, 1, bF1); }                         \
    if ((qi) == 1 && (qj) == 0) { LOAD_A(b, 1); }                              \
    STG;                                                                       \
    if ((qi) == 0 && (qj) == 0)                                                \
      asm volatile("s_waitcnt lgkmcnt(8)" ::: "memory");                       \
    __builtin_amdgcn_s_barrier();                                              \
    if ((WAITN) == 6) asm volatile("s_waitcnt vmcnt(6)" ::: "memory");         \
    if ((WAITN) == 0) asm volatile("s_waitcnt vmcnt(0)" ::: "memory");         \
    asm volatile("s_waitcnt lgkmcnt(0)" ::: "memory");                         \
    __builtin_amdgcn_s_setprio(1);                                             \
    if ((qj) == 0) { MFMA16(qi, 0, bF0); } else { MFMA16(qi, 1, bF1); }        \
    __builtin_amdgcn_s_setprio(0);                                             \
    __builtin_amdgcn_s_barrier();                                              \
  }

#define ITER(kt, LAST)                                                         \
  {                                                                            \
    PHASE(0, 0, 0, STAGE_A((kt) + 1, 1, 1), -1);                               \
    PHASE(0, 0, 1, if (!(LAST)) STAGE_A((kt) + 2, 0, 0), -1);                  \
    PHASE(0, 1, 0, if (!(LAST)) STAGE_B((kt) + 2, 0, 0), -1);                  \
    PHASE(0, 1, 1, if (!(LAST)) STAGE_B((kt) + 2, 1, 0), (LAST) ? 0 : 6);      \
    PHASE(1, 0, 0, if (!(LAST)) STAGE_A((kt) + 2, 1, 0), -1);                  \
    PHASE(1, 0, 1, if (!(LAST)) STAGE_A((kt) + 3, 0, 1), -1);                  \
    PHASE(1, 1, 0, if (!(LAST)) STAGE_B((kt) + 3, 0, 1), -1);                  \
    PHASE(1, 1, 1, if (!(LAST)) STAGE_B((kt) + 3, 1, 1), (LAST) ? -1 : 6);     \
  }

template <int MODE>
__global__ __launch_bounds__(512, 2) void gemm_bt(
    const unsigned short* __restrict__ A, const unsigned short* __restrict__ Bt,
    void* __restrict__ Cv) {
  // A: [2 bufs][256 rows][64 cols] @ elem 0; B: same @ elem 32768.
  // B rows stored qj-permuted: lds row L = qj*128 + wn*32 + jj*16 + lm
  //   <-> global row r = ((L>>5)&3)*64 + (L>>7)*32 + (L&31).
  // Chunk XOR swizzle: LDS[row][pc] = global[row][pc ^ (row&7)] (8-elem chunks).
  __shared__ unsigned short ldsm[65536];  // 128 KiB

  const int t = threadIdx.x;
  const int lane = t & 63;
  const int wave = t >> 6;
  const int wm = wave >> 2;   // 0..1 (M half of block tile)
  const int wn = wave & 3;    // 0..3 (N quarter)
  const int quad = lane >> 4;
  const int lm = lane & 15;
  const int sw = lm & 7;

  // XCD-patch swizzle: grid (8,32) = 256 blocks = 1/CU; each lin%8 class
  // (assumed XCD round-robin) gets a contiguous 4M x 8N tile patch.
  const int lin = blockIdx.y * 8 + blockIdx.x;  // 0..255
  const int cls = lin & 7;
  const int q = lin >> 3;                       // 0..31
  const int mTile = cls * 4 + (q & 3);          // 0..31
  const int nTile = q >> 2;                     // 0..7
  const size_t mBase = (size_t)mTile * 256;
  const size_t nBase = (size_t)nTile * 256;

  // per-thread staging offsets (elements). Sweep covers 64 lds rows x 64 cols:
  // thread t -> lds row base+(t>>3), phys chunk t&7, global chunk swizzled.
  const int lr = t >> 3;
  const int swz = (t & 7) ^ (lr & 7);
  const unsigned short* Ab = A + mBase * GK + lr * GK + swz * 8;
  const unsigned short* Bb =
      Bt + nBase * GK + (lr >> 5) * 64 * GK + (lr & 31) * GK + swz * 8;
  unsigned short* ldsT = ldsm + t * 8;

  // fragment read vaddrs (one per matrix per kk; sub-tiles via imm offsets)
  const unsigned short* pA0 = ldsm + (wm * 128 + lm) * 64 + ((0 + quad) ^ sw) * 8;
  const unsigned short* pA1 = ldsm + (wm * 128 + lm) * 64 + ((4 + quad) ^ sw) * 8;
  const unsigned short* pB0 =
      ldsm + 32768 + (wn * 32 + lm) * 64 + ((0 + quad) ^ sw) * 8;
  const unsigned short* pB1 =
      ldsm + 32768 + (wn * 32 + lm) * 64 + ((4 + quad) ^ sw) * 8;

  short8 aF[4][2];        // current qi half: 4 i' x 2 kk
  short8 bF0[2][2];       // qj=0: 2 jj x 2 kk (held through phase 4 reuse)
  short8 bF1[2][2];       // qj=1
  f32x4 acc[8][4];
#pragma unroll
  for (int i = 0; i < 8; ++i)
#pragma unroll
    for (int j = 0; j < 4; ++j) {
      f32x4 zz = {0.f, 0.f, 0.f, 0.f};
      acc[i][j] = zz;
    }

  // prologue: kt0 all 4 units, then kt1's first 3 units; vmcnt(6) -> kt0 landed
  STAGE_A(0, 0, 0);
  STAGE_B(0, 0, 0);
  STAGE_B(0, 1, 0);
  STAGE_A(0, 1, 0);
  STAGE_A(1, 0, 1);
  STAGE_B(1, 0, 1);
  STAGE_B(1, 1, 1);
  asm volatile("s_waitcnt vmcnt(6)" ::: "memory");
  __builtin_amdgcn_s_barrier();

  const int KT = GK >> 6;  // 32 K-tiles of 64
  int kt = 0;
#pragma unroll 1
  for (; kt + 2 < KT; kt += 2) { ITER(kt, 0); }
  ITER(kt, 1);  // peeled: only ph1 stage, vmcnt(0) at ph4

  // epilogue: C/D layout col=lane&15, row=quad*4+reg  [m89/m91 verified]
#pragma unroll
  for (int i = 0; i < 8; ++i) {
    const size_t row = mBase + wm * 128 + (i >> 2) * 64 + (i & 3) * 16 + quad * 4;
#pragma unroll
    for (int j = 0; j < 4; ++j) {
      const size_t col = nBase + wn * 64 + (j >> 1) * 32 + (j & 1) * 16 + lm;
#pragma unroll
      for (int rg = 0; rg < 4; ++rg) {
        float x = acc[i][j][rg];
        size_t off = (row + rg) * GN + col;
        if (MODE == MODE_F32) {
          ((float*)Cv)[off] = x;
        } else {
          if (MODE == MODE_F16_SIG) x = 1.0f / (1.0f + __expf(-x));
          ((unsigned short*)Cv)[off] = f2h(x);
        }
      }
    }
  }
}

// ---------------- WKV pass 1: per-chunk summary from zero state ------------
__global__ void wkv_pass1(const unsigned short* __restrict__ kk,
                          const unsigned short* __restrict__ vv,
                          const float* __restrict__ tdec,
                          float* __restrict__ pn, float* __restrict__ pd,
                          float* __restrict__ pm, int T, int H, int L) {
  int idx = blockIdx.x * blockDim.x + threadIdx.x;  // [0, B*C*H)
  int h = idx % H;
  int bc = idx / H;
  int c = bc % WKV_C;
  int b = bc / WKV_C;
  const float td = -__expf(tdec[h]);
  size_t base = ((size_t)b * T + (size_t)c * L) * H + h;
  const unsigned short* kp = kk + base;
  const unsigned short* vp = vv + base;
  float num = 0.f, den = 0.f, mx = -1e38f;
#pragma unroll 8
  for (int t = 0; t < L; ++t) {
    float kt = h2f(kp[(size_t)t * H]);
    float vt = h2f(vp[(size_t)t * H]);
    float mtd = mx + td;
    float mfs = fmaxf(mtd, kt);
    float e1s = __expf(mtd - mfs);
    float e2s = __expf(kt - mfs);
    num = e1s * num + e2s * vt;
    den = e1s * den + e2s;
    mx = mfs;
  }
  pn[idx] = num;
  pd[idx] = den;
  pm[idx] = mx;
}

// ---------------- WKV pass 3 (pass2 folded in): prefix + replay, emit y ----
__global__ void wkv_pass3(const unsigned short* __restrict__ kk,
                          const unsigned short* __restrict__ vv,
                          const unsigned short* rr,
                          const float* __restrict__ pn,
                          const float* __restrict__ pd,
                          const float* __restrict__ pm,
                          const float* __restrict__ tdec,
                          const float* __restrict__ tfir, unsigned short* y,
                          int T, int H, int L) {
  int idx = blockIdx.x * blockDim.x + threadIdx.x;  // [0, B*C*H)
  int h = idx % H;
  int bc = idx / H;
  int c = bc % WKV_C;
  int b = bc / WKV_C;
  const float td = -__expf(tdec[h]);
  const float tf = tfir[h];
  // inline chunk-prefix (was pass2): combine chunks 0..c-1, same order/math.
  const float Ltd = td * (float)L;
  float num = 0.f, den = 0.f, mx = -1e38f;
  for (int cp = 0; cp < c; ++cp) {
    size_t o = ((size_t)b * WKV_C + cp) * H + h;
    float mtd = mx + Ltd;
    float cm = pm[o];
    float mnew = fmaxf(mtd, cm);
    float e1 = __expf(mtd - mnew);
    float e2 = __expf(cm - mnew);
    num = e1 * num + e2 * pn[o];
    den = e1 * den + e2 * pd[o];
    mx = mnew;
  }
  size_t base = ((size_t)b * T + (size_t)c * L) * H + h;
  const unsigned short* kp = kk + base;
  const unsigned short* vp = vv + base;
  const unsigned short* rp = rr + base;
  unsigned short* yp = y + base;
#pragma unroll 4
  for (int t = 0; t < L; ++t) {
    size_t o = (size_t)t * H;
    float kt = h2f(kp[o]);
    float vt = h2f(vp[o]);
    float rt = h2f(rp[o]);
    float ktf = kt + tf;
    float mfo = fmaxf(mx, ktf);
    float e1 = __expf(mx - mfo);
    float e2 = __expf(ktf - mfo);
    float out = __fdividef(e1 * num + e2 * vt, e1 * den + e2);
    yp[o] = f2bf(rt * out);
    float mtd = mx + td;
    float mfs = fmaxf(mtd, kt);
    float e1s = __expf(mtd - mfs);
    float e2s = __expf(kt - mfs);
    num = e1s * num + e2s * vt;
    den = e1s * den + e2s;
    mx = mfs;
  }
}

// ---------------------------------------------------------------------------
extern "C" void kernel_launch(void* const* d_in, const int* in_sizes, int n_in,
                              void* d_out, int out_size, void* d_ws,
                              size_t ws_size, hipStream_t stream) {
  const int Bb = 4, T = 2048, H = 2048;
  const int M = Bb * T;      // 8192
  const int L = T / WKV_C;   // 64

  const float* hidden = (const float*)d_in[0];
  const float* time_decay = (const float*)d_in[1];
  const float* time_first = (const float*)d_in[2];
  const float* tmk = (const float*)d_in[3];
  const float* tmv = (const float*)d_in[4];
  const float* tmr = (const float*)d_in[5];
  const float* Wk = (const float*)d_in[6];
  const float* Wv = (const float*)d_in[7];
  const float* Wr = (const float*)d_in[8];
  const float* Wo = (const float*)d_in[9];
  float* out = (float*)d_out;

  const size_t szWT = (size_t)H * H * 2;   // 8.4 MB
  const size_t szMH = (size_t)M * H * 2;   // 33.5 MB
  const size_t need = szWT + 4 * szMH + 1024;
  if (ws_size < need) return;  // diagnostic guard

  char* ws = (char*)d_ws;
  size_t off = 0;
  auto alloc = [&](size_t bytes) {
    char* p = ws + off;
    off += (bytes + 255) & ~(size_t)255;
    return p;
  };
  unsigned short* WT = (unsigned short*)alloc(szWT);
  unsigned short* A1 = (unsigned short*)alloc(szMH);  // xk, later vbuf
  unsigned short* A2 = (unsigned short*)alloc(szMH);  // xv, later rbuf/y
  unsigned short* A3 = (unsigned short*)alloc(szMH);  // xr, later chunk arrays
  unsigned short* A4 = (unsigned short*)alloc(szMH);  // kbuf

  unsigned short* xk = A1;
  unsigned short* xv = A2;
  unsigned short* xr = A3;
  unsigned short* kbuf = A4;
  unsigned short* vbuf = A1;  // xk dead after GEMM-k
  unsigned short* rbuf = A2;  // xv dead after GEMM-v; y in-place later

  // chunk-scan arrays in A3 (xr dead after GEMM-r): 3 MB << 33.5 MB.
  const size_t nCH = (size_t)Bb * WKV_C * H;  // 262144
  float* pn = (float*)A3;
  float* pd = pn + nCH;
  float* pm = pd + nCH;

  const dim3 txG(H / 32, H / 32), txB(32, 8);
  const int H4 = H / 4;
  const dim3 gmG(H / 256, M / 256), gmB(512);

  // fused mix (hidden read once)
  mix3_kernel<<<dim3((M * H4) / 256), dim3(256), 0, stream>>>(
      (const float4*)hidden, (const float4*)tmk, (const float4*)tmv,
      (const float4*)tmr, (ushort4*)xk, (ushort4*)xv, (ushort4*)xr, T, H4);

  // k path
  transpose_cast<<<txG, txB, 0, stream>>>(Wk, WT, H);
  gemm_bt<MODE_F16><<<gmG, gmB, 0, stream>>>(xk, WT, kbuf);
  // v path (writes over dead xk)
  transpose_cast<<<txG, txB, 0, stream>>>(Wv, WT, H);
  gemm_bt<MODE_F16><<<gmG, gmB, 0, stream>>>(xv, WT, vbuf);
  // r path (sigmoid fused; writes over dead xv)
  transpose_cast<<<txG, txB, 0, stream>>>(Wr, WT, H);
  gemm_bt<MODE_F16_SIG><<<gmG, gmB, 0, stream>>>(xr, WT, rbuf);

  // WKV chunked parallel scan (xr region now dead -> chunk arrays there)
  const int nThreads1 = Bb * WKV_C * H;  // 262144
  wkv_pass1<<<dim3(nThreads1 / 256), dim3(256), 0, stream>>>(
      kbuf, vbuf, time_decay, pn, pd, pm, T, H, L);
  wkv_pass3<<<dim3(nThreads1 / 256), dim3(256), 0, stream>>>(
      kbuf, vbuf, rbuf, pn, pd, pm, time_decay, time_first, rbuf, T, H, L);

  // output GEMM: out = y @ Wo (fp32 out)
  transpose_cast<<<txG, txB, 0, stream>>>(Wo, WT, H);
  gemm_bt<MODE_F32><<<gmG, gmB, 0, stream>>>(rbuf, WT, out);
}